// Round 14
// baseline (412.042 us; speedup 1.0000x reference)
//
#include <hip/hip_runtime.h>
#include <math.h>

typedef _Float16 v8h __attribute__((ext_vector_type(8)));
typedef float v4f __attribute__((ext_vector_type(4)));
typedef float v16f __attribute__((ext_vector_type(16)));

// global -> LDS direct DMA, 16B per lane. LDS dest must be wave-uniform base
// + lane*16 (per-lane ptr computed as such); global src is per-lane.
__device__ __forceinline__ void gload_lds16(const _Float16* g, _Float16* l) {
  __builtin_amdgcn_global_load_lds(
      (const __attribute__((address_space(1))) unsigned int*)(const void*)g,
      (__attribute__((address_space(3))) unsigned int*)(void*)l, 16, 0, 0);
}

// ---------------------------------------------------------------- prep (repack + mlp + convert, ONE launch)
// R12 (kept): MLP = 4 parallel blocks, lane-pair per row, batched float4
// loads; prep dropped out of top-5 (was the hidden 50us serial tail R0-R11).
// blocks [0,64):    rc repack, 2 co per block (LDS transpose, coalesced)
// blocks [64,256):  bb repack, conv k=(bx-64)/32, co-group g=(bx-64)%32 (4 co)
// blocks [256,263): dp copy (flat, coalesced)
// blocks [263,267): mlp batch b = bx-263
// blocks [267,1667): NCHW f32 -> NHWC f16 convert (32 ch/thread)
__global__ void __launch_bounds__(256) prep_kernel(
    const float* __restrict__ rc_w, const float* __restrict__ bb_w1,
    const float* __restrict__ bb_w2, const float* __restrict__ dp_w,
    const float* __restrict__ img, const float* __restrict__ sps,
    const float* __restrict__ fc1_w, const float* __restrict__ fc1_b,
    const float* __restrict__ fc2_w, const float* __restrict__ fc2_b,
    const float* __restrict__ se_rw, const float* __restrict__ se_rb,
    const float* __restrict__ se_ew, const float* __restrict__ se_eb,
    _Float16* __restrict__ wrc, _Float16* __restrict__ wbb,
    _Float16* __restrict__ wdp, _Float16* __restrict__ act16,
    float* __restrict__ sig) {
  const int bx = blockIdx.x;
  const int tid = threadIdx.x;
  __shared__ float lds[4612];  // 18,448 B; padded weight stage / mlp buf

  if (bx < 64) {  // ---- rc repack: co-group of 2, src 2x2304 f32 coalesced
    const float* src = rc_w + (size_t)bx * 2 * 2304;
#pragma unroll
    for (int r = 0; r < 18; ++r) {
      int e = r * 256 + tid;            // 0..4607
      int col = e / 2304;               // 0..1
      int rem = e - col * 2304;
      lds[col * 2305 + rem] = src[e];   // +1 pad breaks col-bank aliasing
    }
    __syncthreads();
#pragma unroll
    for (int ro = 0; ro < 3; ++ro) {
      int lidx = ro * 256 + tid;  // 576 slots = 16 c16 x 9 tap x 2 kh x 2 col
      if (lidx < 576) {
        int col = lidx & 1;
        int r = lidx >> 1;        // ((c16*9+tap)*2+kh)
        int kh = r & 1;
        int ct = r >> 1;
        int tap = ct % 9, c16 = ct / 9;
        v8h o;
#pragma unroll
        for (int j = 0; j < 8; ++j)
          o[j] = (_Float16)lds[col * 2305 + (c16 * 16 + kh * 8 + j) * 9 + tap];
        *(v8h*)(wrc + ((size_t)r * 128 + bx * 2 + col) * 8) = o;
      }
    }
  } else if (bx < 256) {  // ---- bb repack: conv k, co-group of 4
    const int t = bx - 64;
    const int k = t >> 5, g = t & 31;
    const float* base = (k < 3) ? (bb_w1 + (size_t)k * 147456)
                                : (bb_w2 + (size_t)(k - 3) * 147456);
    const int cslot = (k < 3) ? (2 * k) : (2 * (k - 3) + 1);
    const float* src = base + (size_t)g * 4 * 1152;
#pragma unroll
    for (int r = 0; r < 18; ++r) {
      int e = r * 256 + tid;            // 0..4607
      int col = e / 1152;               // 0..3
      int rem = e - col * 1152;
      lds[col * 1153 + rem] = src[e];
    }
    __syncthreads();
#pragma unroll
    for (int ro = 0; ro < 3; ++ro) {
      int lidx = ro * 256 + tid;  // 576 slots = 8 c16 x 9 tap x 2 kh x 4 col
      if (lidx < 576) {
        int col = lidx & 3;
        int r = lidx >> 2;        // ((c16*9+tap)*2+kh), c16<8
        int kh = r & 1;
        int ct = r >> 1;
        int tap = ct % 9, c16 = ct / 9;
        v8h o;
#pragma unroll
        for (int j = 0; j < 8; ++j)
          o[j] = (_Float16)lds[col * 1153 + (c16 * 16 + kh * 8 + j) * 9 + tap];
        *(v8h*)(wbb + (size_t)cslot * 147456 + ((size_t)r * 128 + g * 4 + col) * 8) = o;
      }
    }
  } else if (bx < 263) {  // ---- dp: flat, coalesced both sides
    int s3 = (bx - 256) * 256 + tid;  // < 1792
    v8h o;
#pragma unroll
    for (int j = 0; j < 8; ++j) o[j] = (_Float16)dp_w[(size_t)s3 * 8 + j];
    *(v8h*)(wdp + (size_t)s3 * 8) = o;
  } else if (bx < 267) {  // ---- mlp batch b: lane-pair per row, batched loads
    const int b = bx - 263;
    const int wv = tid >> 6, lane = tid & 63;
    const int row = wv * 32 + (lane >> 1);  // 0..127
    const int half = lane & 1;              // 64-col half
    if (tid < 128) lds[tid] = fmaxf(sps[b] * fc1_w[tid] + fc1_b[tid], 0.f);
    __syncthreads();
    {  // stage 1: hm = fc2_w @ x0 + fc2_b -> lds[128..255]
      const float4* wp = (const float4*)(fc2_w + (size_t)row * 128 + half * 64);
      float p = 0.f;
#pragma unroll
      for (int g = 0; g < 2; ++g) {
        float4 w[8];
#pragma unroll
        for (int m = 0; m < 8; ++m) w[m] = wp[g * 8 + m];
#pragma unroll
        for (int m = 0; m < 8; ++m) {
          const int k = half * 64 + g * 32 + m * 4;
          p += w[m].x * lds[k] + w[m].y * lds[k + 1] + w[m].z * lds[k + 2] +
               w[m].w * lds[k + 3];
        }
      }
      p += __shfl_xor(p, 1);
      if (half == 0) lds[128 + row] = p + fc2_b[row];
    }
    __syncthreads();
    {  // stage 2: t = relu(se_rw @ hm + se_rb) -> lds[256..383]
      const float4* wp = (const float4*)(se_rw + (size_t)row * 128 + half * 64);
      float p = 0.f;
#pragma unroll
      for (int g = 0; g < 2; ++g) {
        float4 w[8];
#pragma unroll
        for (int m = 0; m < 8; ++m) w[m] = wp[g * 8 + m];
#pragma unroll
        for (int m = 0; m < 8; ++m) {
          const int k = 128 + half * 64 + g * 32 + m * 4;
          p += w[m].x * lds[k] + w[m].y * lds[k + 1] + w[m].z * lds[k + 2] +
               w[m].w * lds[k + 3];
        }
      }
      p += __shfl_xor(p, 1);
      if (half == 0) lds[256 + row] = fmaxf(p + se_rb[row], 0.f);
    }
    __syncthreads();
    {  // stage 3: se = se_ew @ t + se_eb -> sigmoid -> sig[b*128+row]
      const float4* wp = (const float4*)(se_ew + (size_t)row * 128 + half * 64);
      float p = 0.f;
#pragma unroll
      for (int g = 0; g < 2; ++g) {
        float4 w[8];
#pragma unroll
        for (int m = 0; m < 8; ++m) w[m] = wp[g * 8 + m];
#pragma unroll
        for (int m = 0; m < 8; ++m) {
          const int k = 256 + half * 64 + g * 32 + m * 4;
          p += w[m].x * lds[k] + w[m].y * lds[k + 1] + w[m].z * lds[k + 2] +
               w[m].w * lds[k + 3];
        }
      }
      p += __shfl_xor(p, 1);
      if (half == 0) {
        float v = p + se_eb[row];
        sig[b * 128 + row] = 1.f / (1.f + expf(-v));
      }
    }
  } else {  // ---- convert: 1400 blocks, no LDS use, 32 loads in flight
    const int bid = bx - 267;                      // 0..1399
    const int cq = bid & 7;                        // 32-ch group 0..7
    const int i = (bid >> 3) * 256 + tid;          // 0..44799
    const int n = i / 11200;
    const int hw = i - n * 11200;
    const float* ip = img + (size_t)n * 2867200 + (size_t)(cq * 32) * 11200 + hw;
    float v[32];
#pragma unroll
    for (int k = 0; k < 32; ++k) v[k] = ip[(size_t)k * 11200];
    _Float16* op = act16 + (size_t)i * 256 + cq * 32;
#pragma unroll
    for (int g = 0; g < 4; ++g) {
      v8h o;
#pragma unroll
      for (int j = 0; j < 8; ++j) o[j] = (_Float16)v[g * 8 + j];
      *(v8h*)(op + g * 8) = o;
    }
  }
}

// ---------------------------------------------------------------- 3x3 conv, implicit GEMM, 32x32x16 f16 MFMA
// R14: N64 wave tile to cut LDS reads/MFMA. Cycle model: per CU per chunk the
// DS pipe served 16 waves x 21 ds_read_b128 = 4032 cy (~27us of the 44us rc
// conv -- the dominant term). Wave now computes BOTH cout halves (N64):
// per tap 2 B-frags + 4 MFMAs; with dy-reuse the chunk = 12 A + 18 B = 30
// reads per 36 MFMAs (0.83/MFMA vs 1.17). Per-CU LDS time/chunk 4032->2880cy.
// Unlike R8's failed split: cout stays 64/block (B amortization + FETCH ~28MB
// unchanged), block tile 8h x 32w x 64co, LDS, grid 7x7x8 all unchanged.
// 4 waves (256 thr, wv=wave h-pair), 2 blocks/CU; B via 5 DMA rounds, A via
// 3 VGPR+commit rounds (masked halo -- DMA-unsafe); one barrier per chunk:
//   commit A -> barrier (drains B-DMA(c)) -> issue B-DMA(c+1) + A-pref -> 36 MFMA.
// MODE 0: out = relu((conv + bias)*s + t) * sig_se          (rc conv)
// MODE 1: out = relu(conv*s + t)                            (bb conv1)
// MODE 2: out = relu(xprev + conv*s + t)                    (bb conv2 + residual)
template <int CIN, int MODE>
__global__ void __launch_bounds__(256, 2) conv3x3_kernel(
    const _Float16* __restrict__ act, const _Float16* __restrict__ wr,
    const _Float16* __restrict__ xprev, const float* __restrict__ bias,
    const float* __restrict__ sc, const float* __restrict__ tr,
    const float* __restrict__ sig_se, _Float16* __restrict__ out) {
  constexpr int NCH = CIN / 16;  // 16 (rc) or 8 (bb)
  const int wt = blockIdx.x, ht = blockIdx.y;
  const int n = blockIdx.z >> 1, cg = blockIdx.z & 1;
  const int h0 = ht * 8, w0 = wt * 32;
  const int tid = threadIdx.x;
  const int wave = tid >> 6, lane = tid & 63;
  const int l31 = lane & 31, khalf = lane >> 5;
  const int wv = wave;  // h-pair 0..3

  __shared__ alignas(16) _Float16 ldsA[2][2 * 340 * 8];  // 10,880 B per buf
  __shared__ alignas(16) _Float16 ldsB[2][1152 * 8];     // 18,432 B per buf

  // ---- A staging map: 680 v8h slots (2 parts x 340 pos) over 3 rounds
  size_t goffA[3];
  int loffA[3];
  bool exA[3], okA[3];
#pragma unroll
  for (int it = 0; it < 3; ++it) {
    int slot = it * 256 + tid;
    int pos = slot >> 1, part = slot & 1;  // 2 lanes = 32B contiguous global
    int hh = pos / 34, ww = pos - hh * 34;
    int gh = h0 - 1 + hh, gw = w0 - 1 + ww;
    exA[it] = slot < 680;
    bool inimg = (unsigned)gh < 56u && (unsigned)gw < 200u;
    okA[it] = exA[it] && inimg;
    loffA[it] = (part * 340 + pos) * 8;
    int ghc = okA[it] ? gh : 0, gwc = okA[it] ? gw : 0;
    goffA[it] = (((size_t)n * 56 + ghc) * 200 + gwc) * CIN + part * 8;
  }
  // ---- B staging map: 1152 v8h slots (9 tap x 2 kh x 64 cout) over 5 DMA rounds
  size_t goffB[5];
  bool exB[5];
#pragma unroll
  for (int it = 0; it < 5; ++it) {
    int slot = it * 256 + tid;
    exB[it] = slot < 1152;
    int s = exB[it] ? slot : 0;
    int tap = s >> 7, kh = (s >> 6) & 1, co = s & 63;
    goffB[it] = (((size_t)(tap * 2 + kh)) * 128 + cg * 64 + co) * 8;  // chunk-0
  }

  const v8h zero8 = {(_Float16)0, (_Float16)0, (_Float16)0, (_Float16)0,
                     (_Float16)0, (_Float16)0, (_Float16)0, (_Float16)0};
  v8h preA[3];
#pragma unroll
  for (int it = 0; it < 3; ++it) preA[it] = okA[it] ? *(const v8h*)(act + goffA[it]) : zero8;
  // prologue: B chunk 0 -> buf 0 via DMA
#pragma unroll
  for (int it = 0; it < 5; ++it)
    if (exB[it]) gload_lds16(wr + goffB[it], &ldsB[0][(it * 256 + tid) * 8]);

  v16f acc[2][2];
#pragma unroll
  for (int mt = 0; mt < 2; ++mt)
#pragma unroll
    for (int nt = 0; nt < 2; ++nt)
#pragma unroll
      for (int r = 0; r < 16; ++r) acc[mt][nt][r] = 0.f;

#pragma unroll 1
  for (int c = 0; c < NCH; ++c) {
    _Float16* aB = &ldsA[c & 1][0];
    // commit A chunk c
#pragma unroll
    for (int it = 0; it < 3; ++it)
      if (exA[it]) *(v8h*)(aB + loffA[it]) = preA[it];
    __syncthreads();  // drains B-DMA(c) [vmcnt] + A commits [lgkm]
    if (c + 1 < NCH) {
      // issue next B-DMA (lands during compute; drained at next barrier)
#pragma unroll
      for (int it = 0; it < 5; ++it)
        if (exB[it])
          gload_lds16(wr + goffB[it] + (size_t)(c + 1) * 18432,
                      &ldsB[(c + 1) & 1][(it * 256 + tid) * 8]);
      // prefetch next A to VGPR
#pragma unroll
      for (int it = 0; it < 3; ++it)
        preA[it] = okA[it] ? *(const v8h*)(act + goffA[it] + (size_t)(c + 1) * 16) : zero8;
    }
    // compute: dx outer; 4 A-rows serve 3 dy x 2 mt; 2 B-frags per tap (N64)
    const _Float16* bB = &ldsB[c & 1][0];
#pragma unroll
    for (int dx = 0; dx < 3; ++dx) {
      v8h a[4];
#pragma unroll
      for (int r = 0; r < 4; ++r)
        a[r] = *(const v8h*)(aB + (khalf * 340 + (wv * 2 + r) * 34 + l31 + dx) * 8);
#pragma unroll
      for (int dy = 0; dy < 3; ++dy) {
        const int tap = dy * 3 + dx;
        v8h bf0 = *(const v8h*)(bB + (tap * 128 + khalf * 64 + l31) * 8);
        v8h bf1 = *(const v8h*)(bB + (tap * 128 + khalf * 64 + 32 + l31) * 8);
        acc[0][0] = __builtin_amdgcn_mfma_f32_32x32x16_f16(a[dy], bf0, acc[0][0], 0, 0, 0);
        acc[0][1] = __builtin_amdgcn_mfma_f32_32x32x16_f16(a[dy], bf1, acc[0][1], 0, 0, 0);
        acc[1][0] = __builtin_amdgcn_mfma_f32_32x32x16_f16(a[dy + 1], bf0, acc[1][0], 0, 0, 0);
        acc[1][1] = __builtin_amdgcn_mfma_f32_32x32x16_f16(a[dy + 1], bf1, acc[1][1], 0, 0, 0);
      }
    }
  }

  // epilogue: D layout col(N=cout)=l31, row(M=w-offset)=(r&3)+8*(r>>2)+4*khalf
#pragma unroll
  for (int mt = 0; mt < 2; ++mt) {
    const int h = h0 + wv * 2 + mt;
#pragma unroll
    for (int nt = 0; nt < 2; ++nt) {
      const int cc = cg * 64 + nt * 32 + l31;
      const float s = sc[cc], t = tr[cc];
      float bb = 0.f, sg = 1.f;
      if constexpr (MODE == 0) {
        bb = bias[cc];
        sg = sig_se[n * 128 + cc];
      }
#pragma unroll
      for (int r = 0; r < 16; ++r) {
        const int m = (r & 3) + 8 * (r >> 2) + 4 * khalf;
        const int w = w0 + m;
        if (w < 200) {
          float v = acc[mt][nt][r];
          size_t oidx = (((size_t)n * 56 + h) * 200 + w) * 128 + cc;
          if constexpr (MODE == 0) v = fmaxf((v + bb) * s + t, 0.f) * sg;
          if constexpr (MODE == 1) v = fmaxf(v * s + t, 0.f);
          if constexpr (MODE == 2) v = fmaxf((float)xprev[oidx] + v * s + t, 0.f);
          out[oidx] = (_Float16)v;
        }
      }
    }
  }
}

// ---------------------------------------------------------------- depth proj (MFMA) + fused softmax
// x: [44800][128] f16; wdp: [112][128] f16; dp_b: [112] f32
// depth out: f16 [pos][112] (z-contiguous for gridsample)
__global__ void __launch_bounds__(256) depth_proj_softmax_kernel(
    const _Float16* __restrict__ x, const _Float16* __restrict__ wdp,
    const float* __restrict__ dp_b, _Float16* __restrict__ depth) {
  const int wave = threadIdx.x >> 6, lane = threadIdx.x & 63;
  const int q = lane >> 4, l16 = lane & 15;
  const int pos0 = blockIdx.x * 64 + wave * 16;

  v4f acc[7];
#pragma unroll
  for (int nt = 0; nt < 7; ++nt) {
    float bv = dp_b[nt * 16 + l16];
    acc[nt] = {bv, bv, bv, bv};
  }
#pragma unroll
  for (int c0 = 0; c0 < 128; c0 += 32) {
    v8h a = *(const v8h*)(x + (size_t)(pos0 + l16) * 128 + c0 + q * 8);
#pragma unroll
    for (int nt = 0; nt < 7; ++nt) {
      v8h b = *(const v8h*)(wdp + (size_t)(nt * 16 + l16) * 128 + c0 + q * 8);
      acc[nt] = __builtin_amdgcn_mfma_f32_16x16x32_f16(a, b, acc[nt], 0, 0, 0);
    }
  }
  float m[4];
#pragma unroll
  for (int r = 0; r < 4; ++r) {
    m[r] = acc[0][r];
#pragma unroll
    for (int nt = 1; nt < 7; ++nt) m[r] = fmaxf(m[r], acc[nt][r]);
  }
#pragma unroll
  for (int off = 1; off < 16; off <<= 1)
#pragma unroll
    for (int r = 0; r < 4; ++r) m[r] = fmaxf(m[r], __shfl_xor(m[r], off));
  float s[4] = {0.f, 0.f, 0.f, 0.f};
#pragma unroll
  for (int nt = 0; nt < 7; ++nt)
#pragma unroll
    for (int r = 0; r < 4; ++r) {
      float e = expf(acc[nt][r] - m[r]);
      acc[nt][r] = e;
      s[r] += e;
    }
#pragma unroll
  for (int off = 1; off < 16; off <<= 1)
#pragma unroll
    for (int r = 0; r < 4; ++r) s[r] += __shfl_xor(s[r], off);
#pragma unroll
  for (int r = 0; r < 4; ++r) {
    const float inv = 1.f / s[r];
    const size_t p = pos0 + q * 4 + r;
#pragma unroll
    for (int nt = 0; nt < 7; ++nt)
      depth[p * 112 + nt * 16 + l16] = (_Float16)(acc[nt][r] * inv);
  }
}

// ---------------------------------------------------------------- trilinear grid sample (C=1)
// R10: XCD-pinned by volume. Each n's depth volume is 2.5 MB (fits one XCD's
// 4 MiB L2, ~200x line reuse); bijective swizzle: XCD x serves n = x>>1 only.
__global__ void __launch_bounds__(256) gridsample_kernel(
    const float* __restrict__ grids, const _Float16* __restrict__ depth,
    float* __restrict__ out) {
  const int b = blockIdx.x;
  const int x = b & 7, s = b >> 3;                 // XCD id (dispatch %8), slot
  const int i0 = (x >> 1) * 1024 + (x & 1) * 512 + s;  // bijective on [0,4096)
  const int i = i0 * 256 + (int)threadIdx.x;
  const int n = i >> 18;
  const float gx = grids[(size_t)i * 3];
  const float gy = grids[(size_t)i * 3 + 1];
  const float gz = grids[(size_t)i * 3 + 2];
  const float ix = (gx + 1.f) * 100.f - 0.5f;
  const float iy = (gy + 1.f) * 28.f - 0.5f;
  const float iz = (gz + 1.f) * 56.f - 0.5f;
  const float xf = floorf(ix), yf = floorf(iy), zf = floorf(iz);
  const int x0 = (int)xf, y0 = (int)yf, z0 = (int)zf;
  const float fx = ix - xf, fy = iy - yf, fz = iz - zf;
  const bool zv0 = (unsigned)z0 < 112u;
  const bool zv1 = (unsigned)(z0 + 1) < 112u;
  const float wz0 = 1.f - fz, wz1 = fz;
  float acc = 0.f;
#pragma unroll
  for (int dy = 0; dy < 2; ++dy) {
    const int yi = y0 + dy;
    const float wy = dy ? fy : 1.f - fy;
#pragma unroll
    for (int dx = 0; dx < 2; ++dx) {
      const int xi = x0 + dx;
      const float wx = dx ? fx : 1.f - fx;
      if ((unsigned)xi < 200u && (unsigned)yi < 56u) {
        const _Float16* bp = depth + ((size_t)n * 11200 + yi * 200 + xi) * 112;
        float v0 = zv0 ? (float)bp[z0] : 0.f;
        float v1 = zv1 ? (float)bp[z0 + 1] : 0.f;
        acc += (wx * wy) * (wz0 * v0 + wz1 * v1);
      }
    }
  }
  out[i] = acc;
}

// ---------------------------------------------------------------- launch
extern "C" void kernel_launch(void* const* d_in, const int* in_sizes, int n_in,
                              void* d_out, int out_size, void* d_ws, size_t ws_size,
                              hipStream_t stream) {
  (void)in_sizes; (void)n_in; (void)out_size; (void)ws_size;
  const float* img = (const float*)d_in[0];
  const float* sps = (const float*)d_in[1];
  const float* grids = (const float*)d_in[2];
  const float* rc_w = (const float*)d_in[3];
  const float* rc_b = (const float*)d_in[4];
  const float* rc_s = (const float*)d_in[5];
  const float* rc_t = (const float*)d_in[6];
  const float* fc1_w = (const float*)d_in[7];
  const float* fc1_b = (const float*)d_in[8];
  const float* fc2_w = (const float*)d_in[9];
  const float* fc2_b = (const float*)d_in[10];
  const float* se_rw = (const float*)d_in[11];
  const float* se_rb = (const float*)d_in[12];
  const float* se_ew = (const float*)d_in[13];
  const float* se_eb = (const float*)d_in[14];
  const float* bb_w1 = (const float*)d_in[15];
  const float* bb_s1 = (const float*)d_in[16];
  const float* bb_t1 = (const float*)d_in[17];
  const float* bb_w2 = (const float*)d_in[18];
  const float* bb_s2 = (const float*)d_in[19];
  const float* bb_t2 = (const float*)d_in[20];
  const float* dp_w = (const float*)d_in[21];
  const float* dp_b = (const float*)d_in[22];
  float* outp = (float*)d_out;

  char* ws = (char*)d_ws;
  _Float16* act16 = (_Float16*)(ws + 0);
  _Float16* depth16 = (_Float16*)(ws + 0);  // reuses act16 slot (act16 dead post rc-conv)
  _Float16* xa = (_Float16*)(ws + 23068672);
  _Float16* xb = (_Float16*)(ws + 23068672 + 11534336);
  _Float16* yb = (_Float16*)(ws + 23068672 + 2 * 11534336);
  _Float16* wrc = (_Float16*)(ws + 57671680);           // 589,824 B
  _Float16* wdp = (_Float16*)(ws + 57671680 + 589824);  // 28,672 B
  _Float16* wbb = (_Float16*)(ws + 58327040);           // 1,769,472 B
  float* sig = (float*)(ws + 58327040 + 1769472);       // 2,048 B

  prep_kernel<<<dim3(1667), 256, 0, stream>>>(
      rc_w, bb_w1, bb_w2, dp_w, img, sps, fc1_w, fc1_b, fc2_w, fc2_b, se_rw, se_rb,
      se_ew, se_eb, wrc, wbb, wdp, act16, sig);

  dim3 cgrid(7, 7, 8);  // 8h x 32w x 64cout, z = n*2 + cg, 392 blocks x 4 waves
  conv3x3_kernel<256, 0><<<cgrid, 256, 0, stream>>>(act16, wrc, nullptr, rc_b, rc_s,
                                                    rc_t, sig, xa);
  _Float16* xcur = xa;
  _Float16* xnxt = xb;
  for (int i = 0; i < 3; ++i) {
    conv3x3_kernel<128, 1><<<cgrid, 256, 0, stream>>>(
        xcur, wbb + (size_t)(2 * i) * 147456, nullptr, nullptr, bb_s1 + i * 128,
        bb_t1 + i * 128, nullptr, yb);
    conv3x3_kernel<128, 2><<<cgrid, 256, 0, stream>>>(
        yb, wbb + (size_t)(2 * i + 1) * 147456, xcur, nullptr, bb_s2 + i * 128,
        bb_t2 + i * 128, nullptr, xnxt);
    _Float16* t = xcur;
    xcur = xnxt;
    xnxt = t;
  }

  depth_proj_softmax_kernel<<<dim3(700), 256, 0, stream>>>(xcur, wdp, dp_b, depth16);
  gridsample_kernel<<<dim3(4096), 256, 0, stream>>>(grids, depth16, outp);
}

// Round 15
// 381.721 us; speedup vs baseline: 1.0794x; 1.0794x over previous
//
#include <hip/hip_runtime.h>
#include <math.h>

typedef _Float16 v8h __attribute__((ext_vector_type(8)));
typedef float v4f __attribute__((ext_vector_type(4)));
typedef float v16f __attribute__((ext_vector_type(16)));

// global -> LDS direct DMA, 16B per lane. LDS dest must be wave-uniform base
// + lane*16 (per-lane ptr computed as such); global src is per-lane.
__device__ __forceinline__ void gload_lds16(const _Float16* g, _Float16* l) {
  __builtin_amdgcn_global_load_lds(
      (const __attribute__((address_space(1))) unsigned int*)(const void*)g,
      (__attribute__((address_space(3))) unsigned int*)(void*)l, 16, 0, 0);
}

// ---------------------------------------------------------------- prep (repack + mlp + convert, ONE launch)
// R12 (kept): MLP = 4 parallel blocks, lane-pair per row, batched float4
// loads; prep dropped out of top-5 (was the hidden 50us serial tail R0-R11).
// blocks [0,64):    rc repack, 2 co per block (LDS transpose, coalesced)
// blocks [64,256):  bb repack, conv k=(bx-64)/32, co-group g=(bx-64)%32 (4 co)
// blocks [256,263): dp copy (flat, coalesced)
// blocks [263,267): mlp batch b = bx-263
// blocks [267,1667): NCHW f32 -> NHWC f16 convert (32 ch/thread)
__global__ void __launch_bounds__(256) prep_kernel(
    const float* __restrict__ rc_w, const float* __restrict__ bb_w1,
    const float* __restrict__ bb_w2, const float* __restrict__ dp_w,
    const float* __restrict__ img, const float* __restrict__ sps,
    const float* __restrict__ fc1_w, const float* __restrict__ fc1_b,
    const float* __restrict__ fc2_w, const float* __restrict__ fc2_b,
    const float* __restrict__ se_rw, const float* __restrict__ se_rb,
    const float* __restrict__ se_ew, const float* __restrict__ se_eb,
    _Float16* __restrict__ wrc, _Float16* __restrict__ wbb,
    _Float16* __restrict__ wdp, _Float16* __restrict__ act16,
    float* __restrict__ sig) {
  const int bx = blockIdx.x;
  const int tid = threadIdx.x;
  __shared__ float lds[4612];  // 18,448 B; padded weight stage / mlp buf

  if (bx < 64) {  // ---- rc repack: co-group of 2, src 2x2304 f32 coalesced
    const float* src = rc_w + (size_t)bx * 2 * 2304;
#pragma unroll
    for (int r = 0; r < 18; ++r) {
      int e = r * 256 + tid;            // 0..4607
      int col = e / 2304;               // 0..1
      int rem = e - col * 2304;
      lds[col * 2305 + rem] = src[e];   // +1 pad breaks col-bank aliasing
    }
    __syncthreads();
#pragma unroll
    for (int ro = 0; ro < 3; ++ro) {
      int lidx = ro * 256 + tid;  // 576 slots = 16 c16 x 9 tap x 2 kh x 2 col
      if (lidx < 576) {
        int col = lidx & 1;
        int r = lidx >> 1;        // ((c16*9+tap)*2+kh)
        int kh = r & 1;
        int ct = r >> 1;
        int tap = ct % 9, c16 = ct / 9;
        v8h o;
#pragma unroll
        for (int j = 0; j < 8; ++j)
          o[j] = (_Float16)lds[col * 2305 + (c16 * 16 + kh * 8 + j) * 9 + tap];
        *(v8h*)(wrc + ((size_t)r * 128 + bx * 2 + col) * 8) = o;
      }
    }
  } else if (bx < 256) {  // ---- bb repack: conv k, co-group of 4
    const int t = bx - 64;
    const int k = t >> 5, g = t & 31;
    const float* base = (k < 3) ? (bb_w1 + (size_t)k * 147456)
                                : (bb_w2 + (size_t)(k - 3) * 147456);
    const int cslot = (k < 3) ? (2 * k) : (2 * (k - 3) + 1);
    const float* src = base + (size_t)g * 4 * 1152;
#pragma unroll
    for (int r = 0; r < 18; ++r) {
      int e = r * 256 + tid;            // 0..4607
      int col = e / 1152;               // 0..3
      int rem = e - col * 1152;
      lds[col * 1153 + rem] = src[e];
    }
    __syncthreads();
#pragma unroll
    for (int ro = 0; ro < 3; ++ro) {
      int lidx = ro * 256 + tid;  // 576 slots = 8 c16 x 9 tap x 2 kh x 4 col
      if (lidx < 576) {
        int col = lidx & 3;
        int r = lidx >> 2;        // ((c16*9+tap)*2+kh), c16<8
        int kh = r & 1;
        int ct = r >> 1;
        int tap = ct % 9, c16 = ct / 9;
        v8h o;
#pragma unroll
        for (int j = 0; j < 8; ++j)
          o[j] = (_Float16)lds[col * 1153 + (c16 * 16 + kh * 8 + j) * 9 + tap];
        *(v8h*)(wbb + (size_t)cslot * 147456 + ((size_t)r * 128 + g * 4 + col) * 8) = o;
      }
    }
  } else if (bx < 263) {  // ---- dp: flat, coalesced both sides
    int s3 = (bx - 256) * 256 + tid;  // < 1792
    v8h o;
#pragma unroll
    for (int j = 0; j < 8; ++j) o[j] = (_Float16)dp_w[(size_t)s3 * 8 + j];
    *(v8h*)(wdp + (size_t)s3 * 8) = o;
  } else if (bx < 267) {  // ---- mlp batch b: lane-pair per row, batched loads
    const int b = bx - 263;
    const int wv = tid >> 6, lane = tid & 63;
    const int row = wv * 32 + (lane >> 1);  // 0..127
    const int half = lane & 1;              // 64-col half
    if (tid < 128) lds[tid] = fmaxf(sps[b] * fc1_w[tid] + fc1_b[tid], 0.f);
    __syncthreads();
    {  // stage 1: hm = fc2_w @ x0 + fc2_b -> lds[128..255]
      const float4* wp = (const float4*)(fc2_w + (size_t)row * 128 + half * 64);
      float p = 0.f;
#pragma unroll
      for (int g = 0; g < 2; ++g) {
        float4 w[8];
#pragma unroll
        for (int m = 0; m < 8; ++m) w[m] = wp[g * 8 + m];
#pragma unroll
        for (int m = 0; m < 8; ++m) {
          const int k = half * 64 + g * 32 + m * 4;
          p += w[m].x * lds[k] + w[m].y * lds[k + 1] + w[m].z * lds[k + 2] +
               w[m].w * lds[k + 3];
        }
      }
      p += __shfl_xor(p, 1);
      if (half == 0) lds[128 + row] = p + fc2_b[row];
    }
    __syncthreads();
    {  // stage 2: t = relu(se_rw @ hm + se_rb) -> lds[256..383]
      const float4* wp = (const float4*)(se_rw + (size_t)row * 128 + half * 64);
      float p = 0.f;
#pragma unroll
      for (int g = 0; g < 2; ++g) {
        float4 w[8];
#pragma unroll
        for (int m = 0; m < 8; ++m) w[m] = wp[g * 8 + m];
#pragma unroll
        for (int m = 0; m < 8; ++m) {
          const int k = 128 + half * 64 + g * 32 + m * 4;
          p += w[m].x * lds[k] + w[m].y * lds[k + 1] + w[m].z * lds[k + 2] +
               w[m].w * lds[k + 3];
        }
      }
      p += __shfl_xor(p, 1);
      if (half == 0) lds[256 + row] = fmaxf(p + se_rb[row], 0.f);
    }
    __syncthreads();
    {  // stage 3: se = se_ew @ t + se_eb -> sigmoid -> sig[b*128+row]
      const float4* wp = (const float4*)(se_ew + (size_t)row * 128 + half * 64);
      float p = 0.f;
#pragma unroll
      for (int g = 0; g < 2; ++g) {
        float4 w[8];
#pragma unroll
        for (int m = 0; m < 8; ++m) w[m] = wp[g * 8 + m];
#pragma unroll
        for (int m = 0; m < 8; ++m) {
          const int k = 256 + half * 64 + g * 32 + m * 4;
          p += w[m].x * lds[k] + w[m].y * lds[k + 1] + w[m].z * lds[k + 2] +
               w[m].w * lds[k + 3];
        }
      }
      p += __shfl_xor(p, 1);
      if (half == 0) {
        float v = p + se_eb[row];
        sig[b * 128 + row] = 1.f / (1.f + expf(-v));
      }
    }
  } else {  // ---- convert: 1400 blocks, no LDS use, 32 loads in flight
    const int bid = bx - 267;                      // 0..1399
    const int cq = bid & 7;                        // 32-ch group 0..7
    const int i = (bid >> 3) * 256 + tid;          // 0..44799
    const int n = i / 11200;
    const int hw = i - n * 11200;
    const float* ip = img + (size_t)n * 2867200 + (size_t)(cq * 32) * 11200 + hw;
    float v[32];
#pragma unroll
    for (int k = 0; k < 32; ++k) v[k] = ip[(size_t)k * 11200];
    _Float16* op = act16 + (size_t)i * 256 + cq * 32;
#pragma unroll
    for (int g = 0; g < 4; ++g) {
      v8h o;
#pragma unroll
      for (int j = 0; j < 8; ++j) o[j] = (_Float16)v[g * 8 + j];
      *(v8h*)(op + g * 8) = o;
    }
  }
}

// ---------------------------------------------------------------- 3x3 conv, implicit GEMM, 32x32x16 f16 MFMA
// R15: exact R13 conv (best measured: 389.8 total; rc 43.9) + XCD-pinned flat
// grid. R14's N64 tile regressed (occupancy 23->12.5%, VGPR 88) -- conv
// structure CLOSED at the R13 config after 10 variants. Swizzle: 392 blocks =
// 8 z-panels x 49 tiles; zz = fid&7 (dispatch round-robins XCDs %8) -> each
// XCD owns one (n,cg) panel; its B slice (295KB) + act slice stay in its
// private L2. R8 measured FETCH 28->24MB with this mapping (pure blockIdx
// permutation; correctness unaffected).
// Tile: 8h x 32w x 64cout, 512 thr / 8 waves, wave 2h x 32w x 32cout.
// B via 3 DMA rounds (LDS-linear, unmasked), A via 2 VGPR+commit rounds
// (masked halo -- DMA-unsafe); one barrier per chunk:
//   commit A -> barrier (drains B-DMA(c)) -> issue B-DMA(c+1) + A-pref -> compute.
// MODE 0: out = relu((conv + bias)*s + t) * sig_se          (rc conv)
// MODE 1: out = relu(conv*s + t)                            (bb conv1)
// MODE 2: out = relu(xprev + conv*s + t)                    (bb conv2 + residual)
template <int CIN, int MODE>
__global__ void __launch_bounds__(512, 4) conv3x3_kernel(
    const _Float16* __restrict__ act, const _Float16* __restrict__ wr,
    const _Float16* __restrict__ xprev, const float* __restrict__ bias,
    const float* __restrict__ sc, const float* __restrict__ tr,
    const float* __restrict__ sig_se, _Float16* __restrict__ out) {
  constexpr int NCH = CIN / 16;  // 16 (rc) or 8 (bb)
  const int fid = blockIdx.x;
  const int zz = fid & 7;        // XCD-pinned z-panel (n,cg)
  const int tt = fid >> 3;       // 0..48
  const int ht = tt / 7, wt = tt - ht * 7;
  const int n = zz >> 1, cg = zz & 1;
  const int h0 = ht * 8, w0 = wt * 32;
  const int tid = threadIdx.x;
  const int wave = tid >> 6, lane = tid & 63;
  const int l31 = lane & 31, khalf = lane >> 5;
  const int wv = wave >> 1, kc = wave & 1;

  __shared__ alignas(16) _Float16 ldsA[2][2 * 340 * 8];  // 10,880 B per buf
  __shared__ alignas(16) _Float16 ldsB[2][1152 * 8];     // 18,432 B per buf

  // ---- A staging map: 680 v8h slots (2 parts x 340 pos) over 2 rounds
  size_t goffA[2];
  int loffA[2];
  bool exA[2], okA[2];
#pragma unroll
  for (int it = 0; it < 2; ++it) {
    int slot = it * 512 + tid;
    int pos = slot >> 1, part = slot & 1;  // 2 lanes = 32B contiguous global
    int hh = pos / 34, ww = pos - hh * 34;
    int gh = h0 - 1 + hh, gw = w0 - 1 + ww;
    exA[it] = slot < 680;
    bool inimg = (unsigned)gh < 56u && (unsigned)gw < 200u;
    okA[it] = exA[it] && inimg;
    loffA[it] = (part * 340 + pos) * 8;
    int ghc = okA[it] ? gh : 0, gwc = okA[it] ? gw : 0;
    goffA[it] = (((size_t)n * 56 + ghc) * 200 + gwc) * CIN + part * 8;
  }
  // ---- B staging map: 1152 v8h slots (9 tap x 2 kh x 64 cout) over 3 rounds.
  //      LDS dest slot*16B == existing layout -> DMA-able (always in-bounds).
  size_t goffB[3];
  bool exB[3];
#pragma unroll
  for (int it = 0; it < 3; ++it) {
    int slot = it * 512 + tid;
    exB[it] = slot < 1152;
    int s = exB[it] ? slot : 0;
    int tap = s >> 7, kh = (s >> 6) & 1, co = s & 63;
    goffB[it] = (((size_t)(tap * 2 + kh)) * 128 + cg * 64 + co) * 8;  // chunk-0
  }

  const v8h zero8 = {(_Float16)0, (_Float16)0, (_Float16)0, (_Float16)0,
                     (_Float16)0, (_Float16)0, (_Float16)0, (_Float16)0};
  v8h preA[2];
#pragma unroll
  for (int it = 0; it < 2; ++it) preA[it] = okA[it] ? *(const v8h*)(act + goffA[it]) : zero8;
  // prologue: B chunk 0 -> buf 0 via DMA
#pragma unroll
  for (int it = 0; it < 3; ++it)
    if (exB[it]) gload_lds16(wr + goffB[it], &ldsB[0][(it * 512 + tid) * 8]);

  v16f acc[2];
#pragma unroll
  for (int mt = 0; mt < 2; ++mt)
#pragma unroll
    for (int r = 0; r < 16; ++r) acc[mt][r] = 0.f;

#pragma unroll 1
  for (int c = 0; c < NCH; ++c) {
    _Float16* aB = &ldsA[c & 1][0];
    // commit A chunk c (prev reader of this buffer finished 2 barriers ago)
#pragma unroll
    for (int it = 0; it < 2; ++it)
      if (exA[it]) *(v8h*)(aB + loffA[it]) = preA[it];
    __syncthreads();  // drains B-DMA(c) [vmcnt] + A commits [lgkm]
    if (c + 1 < NCH) {
      // issue next B-DMA (lands during compute; drained at next barrier)
#pragma unroll
      for (int it = 0; it < 3; ++it)
        if (exB[it])
          gload_lds16(wr + goffB[it] + (size_t)(c + 1) * 18432,
                      &ldsB[(c + 1) & 1][(it * 512 + tid) * 8]);
      // prefetch next A to VGPR (consumed at next iteration's commit)
#pragma unroll
      for (int it = 0; it < 2; ++it)
        preA[it] = okA[it] ? *(const v8h*)(act + goffA[it] + (size_t)(c + 1) * 16) : zero8;
    }
    // compute: dx outer, 4 A-rows reused across dy (6 MFMAs per 4 A-reads)
    const _Float16* bB = &ldsB[c & 1][0];
#pragma unroll
    for (int dx = 0; dx < 3; ++dx) {
      v8h a[4];
#pragma unroll
      for (int r = 0; r < 4; ++r)
        a[r] = *(const v8h*)(aB + (khalf * 340 + (wv * 2 + r) * 34 + l31 + dx) * 8);
#pragma unroll
      for (int dy = 0; dy < 3; ++dy) {
        v8h bf = *(const v8h*)(bB + ((dy * 3 + dx) * 128 + khalf * 64 + kc * 32 + l31) * 8);
        acc[0] = __builtin_amdgcn_mfma_f32_32x32x16_f16(a[dy], bf, acc[0], 0, 0, 0);
        acc[1] = __builtin_amdgcn_mfma_f32_32x32x16_f16(a[dy + 1], bf, acc[1], 0, 0, 0);
      }
    }
  }

  // epilogue: D layout col(N=cout)=l31, row(M=w-offset)=(r&3)+8*(r>>2)+4*khalf
#pragma unroll
  for (int mt = 0; mt < 2; ++mt) {
    const int h = h0 + wv * 2 + mt;
    const int cc = cg * 64 + kc * 32 + l31;
    const float s = sc[cc], t = tr[cc];
    float bb = 0.f, sg = 1.f;
    if constexpr (MODE == 0) {
      bb = bias[cc];
      sg = sig_se[n * 128 + cc];
    }
#pragma unroll
    for (int r = 0; r < 16; ++r) {
      const int m = (r & 3) + 8 * (r >> 2) + 4 * khalf;
      const int w = w0 + m;
      if (w < 200) {
        float v = acc[mt][r];
        size_t oidx = (((size_t)n * 56 + h) * 200 + w) * 128 + cc;
        if constexpr (MODE == 0) v = fmaxf((v + bb) * s + t, 0.f) * sg;
        if constexpr (MODE == 1) v = fmaxf(v * s + t, 0.f);
        if constexpr (MODE == 2) v = fmaxf((float)xprev[oidx] + v * s + t, 0.f);
        out[oidx] = (_Float16)v;
      }
    }
  }
}

// ---------------------------------------------------------------- depth proj (MFMA) + fused softmax
// x: [44800][128] f16; wdp: [112][128] f16; dp_b: [112] f32
// depth out: f16 [pos][112] (z-contiguous for gridsample)
__global__ void __launch_bounds__(256) depth_proj_softmax_kernel(
    const _Float16* __restrict__ x, const _Float16* __restrict__ wdp,
    const float* __restrict__ dp_b, _Float16* __restrict__ depth) {
  const int wave = threadIdx.x >> 6, lane = threadIdx.x & 63;
  const int q = lane >> 4, l16 = lane & 15;
  const int pos0 = blockIdx.x * 64 + wave * 16;

  v4f acc[7];
#pragma unroll
  for (int nt = 0; nt < 7; ++nt) {
    float bv = dp_b[nt * 16 + l16];
    acc[nt] = {bv, bv, bv, bv};
  }
#pragma unroll
  for (int c0 = 0; c0 < 128; c0 += 32) {
    v8h a = *(const v8h*)(x + (size_t)(pos0 + l16) * 128 + c0 + q * 8);
#pragma unroll
    for (int nt = 0; nt < 7; ++nt) {
      v8h b = *(const v8h*)(wdp + (size_t)(nt * 16 + l16) * 128 + c0 + q * 8);
      acc[nt] = __builtin_amdgcn_mfma_f32_16x16x32_f16(a, b, acc[nt], 0, 0, 0);
    }
  }
  float m[4];
#pragma unroll
  for (int r = 0; r < 4; ++r) {
    m[r] = acc[0][r];
#pragma unroll
    for (int nt = 1; nt < 7; ++nt) m[r] = fmaxf(m[r], acc[nt][r]);
  }
#pragma unroll
  for (int off = 1; off < 16; off <<= 1)
#pragma unroll
    for (int r = 0; r < 4; ++r) m[r] = fmaxf(m[r], __shfl_xor(m[r], off));
  float s[4] = {0.f, 0.f, 0.f, 0.f};
#pragma unroll
  for (int nt = 0; nt < 7; ++nt)
#pragma unroll
    for (int r = 0; r < 4; ++r) {
      float e = expf(acc[nt][r] - m[r]);
      acc[nt][r] = e;
      s[r] += e;
    }
#pragma unroll
  for (int off = 1; off < 16; off <<= 1)
#pragma unroll
    for (int r = 0; r < 4; ++r) s[r] += __shfl_xor(s[r], off);
#pragma unroll
  for (int r = 0; r < 4; ++r) {
    const float inv = 1.f / s[r];
    const size_t p = pos0 + q * 4 + r;
#pragma unroll
    for (int nt = 0; nt < 7; ++nt)
      depth[p * 112 + nt * 16 + l16] = (_Float16)(acc[nt][r] * inv);
  }
}

// ---------------------------------------------------------------- trilinear grid sample (C=1)
// R10: XCD-pinned by volume. Each n's depth volume is 2.5 MB (fits one XCD's
// 4 MiB L2, ~200x line reuse); bijective swizzle: XCD x serves n = x>>1 only.
__global__ void __launch_bounds__(256) gridsample_kernel(
    const float* __restrict__ grids, const _Float16* __restrict__ depth,
    float* __restrict__ out) {
  const int b = blockIdx.x;
  const int x = b & 7, s = b >> 3;                 // XCD id (dispatch %8), slot
  const int i0 = (x >> 1) * 1024 + (x & 1) * 512 + s;  // bijective on [0,4096)
  const int i = i0 * 256 + (int)threadIdx.x;
  const int n = i >> 18;
  const float gx = grids[(size_t)i * 3];
  const float gy = grids[(size_t)i * 3 + 1];
  const float gz = grids[(size_t)i * 3 + 2];
  const float ix = (gx + 1.f) * 100.f - 0.5f;
  const float iy = (gy + 1.f) * 28.f - 0.5f;
  const float iz = (gz + 1.f) * 56.f - 0.5f;
  const float xf = floorf(ix), yf = floorf(iy), zf = floorf(iz);
  const int x0 = (int)xf, y0 = (int)yf, z0 = (int)zf;
  const float fx = ix - xf, fy = iy - yf, fz = iz - zf;
  const bool zv0 = (unsigned)z0 < 112u;
  const bool zv1 = (unsigned)(z0 + 1) < 112u;
  const float wz0 = 1.f - fz, wz1 = fz;
  float acc = 0.f;
#pragma unroll
  for (int dy = 0; dy < 2; ++dy) {
    const int yi = y0 + dy;
    const float wy = dy ? fy : 1.f - fy;
#pragma unroll
    for (int dx = 0; dx < 2; ++dx) {
      const int xi = x0 + dx;
      const float wx = dx ? fx : 1.f - fx;
      if ((unsigned)xi < 200u && (unsigned)yi < 56u) {
        const _Float16* bp = depth + ((size_t)n * 11200 + yi * 200 + xi) * 112;
        float v0 = zv0 ? (float)bp[z0] : 0.f;
        float v1 = zv1 ? (float)bp[z0 + 1] : 0.f;
        acc += (wx * wy) * (wz0 * v0 + wz1 * v1);
      }
    }
  }
  out[i] = acc;
}

// ---------------------------------------------------------------- launch
extern "C" void kernel_launch(void* const* d_in, const int* in_sizes, int n_in,
                              void* d_out, int out_size, void* d_ws, size_t ws_size,
                              hipStream_t stream) {
  (void)in_sizes; (void)n_in; (void)out_size; (void)ws_size;
  const float* img = (const float*)d_in[0];
  const float* sps = (const float*)d_in[1];
  const float* grids = (const float*)d_in[2];
  const float* rc_w = (const float*)d_in[3];
  const float* rc_b = (const float*)d_in[4];
  const float* rc_s = (const float*)d_in[5];
  const float* rc_t = (const float*)d_in[6];
  const float* fc1_w = (const float*)d_in[7];
  const float* fc1_b = (const float*)d_in[8];
  const float* fc2_w = (const float*)d_in[9];
  const float* fc2_b = (const float*)d_in[10];
  const float* se_rw = (const float*)d_in[11];
  const float* se_rb = (const float*)d_in[12];
  const float* se_ew = (const float*)d_in[13];
  const float* se_eb = (const float*)d_in[14];
  const float* bb_w1 = (const float*)d_in[15];
  const float* bb_s1 = (const float*)d_in[16];
  const float* bb_t1 = (const float*)d_in[17];
  const float* bb_w2 = (const float*)d_in[18];
  const float* bb_s2 = (const float*)d_in[19];
  const float* bb_t2 = (const float*)d_in[20];
  const float* dp_w = (const float*)d_in[21];
  const float* dp_b = (const float*)d_in[22];
  float* outp = (float*)d_out;

  char* ws = (char*)d_ws;
  _Float16* act16 = (_Float16*)(ws + 0);
  _Float16* depth16 = (_Float16*)(ws + 0);  // reuses act16 slot (act16 dead post rc-conv)
  _Float16* xa = (_Float16*)(ws + 23068672);
  _Float16* xb = (_Float16*)(ws + 23068672 + 11534336);
  _Float16* yb = (_Float16*)(ws + 23068672 + 2 * 11534336);
  _Float16* wrc = (_Float16*)(ws + 57671680);           // 589,824 B
  _Float16* wdp = (_Float16*)(ws + 57671680 + 589824);  // 28,672 B
  _Float16* wbb = (_Float16*)(ws + 58327040);           // 1,769,472 B
  float* sig = (float*)(ws + 58327040 + 1769472);       // 2,048 B

  prep_kernel<<<dim3(1667), 256, 0, stream>>>(
      rc_w, bb_w1, bb_w2, dp_w, img, sps, fc1_w, fc1_b, fc2_w, fc2_b, se_rw, se_rb,
      se_ew, se_eb, wrc, wbb, wdp, act16, sig);

  dim3 cgrid(392);  // flat, XCD-pinned: zz = fid&7, tile = fid>>3; 8 waves/blk
  conv3x3_kernel<256, 0><<<cgrid, 512, 0, stream>>>(act16, wrc, nullptr, rc_b, rc_s,
                                                    rc_t, sig, xa);
  _Float16* xcur = xa;
  _Float16* xnxt = xb;
  for (int i = 0; i < 3; ++i) {
    conv3x3_kernel<128, 1><<<cgrid, 512, 0, stream>>>(
        xcur, wbb + (size_t)(2 * i) * 147456, nullptr, nullptr, bb_s1 + i * 128,
        bb_t1 + i * 128, nullptr, yb);
    conv3x3_kernel<128, 2><<<cgrid, 512, 0, stream>>>(
        yb, wbb + (size_t)(2 * i + 1) * 147456, xcur, nullptr, bb_s2 + i * 128,
        bb_t2 + i * 128, nullptr, xnxt);
    _Float16* t = xcur;
    xcur = xnxt;
    xnxt = t;
  }

  depth_proj_softmax_kernel<<<dim3(700), 256, 0, stream>>>(xcur, wdp, dp_b, depth16);
  gridsample_kernel<<<dim3(4096), 256, 0, stream>>>(grids, depth16, outp);
}